// Round 1
// baseline (789.495 us; speedup 1.0000x reference)
//
#include <hip/hip_runtime.h>
#include <cstdint>
#include <cstddef>

#define B_   8
#define E_   16
#define CIN_ 64
#define C_   64
#define HW_  4096

// selu(x) = scale*x (x>0) ; scale*alpha*(exp(x)-1) (x<=0)
__device__ __forceinline__ float selu_f(float v) {
    const float kAlphaScale = 1.7580993408473766f;  // alpha*scale
    const float kScale      = 1.0507009873554805f;
    return v > 0.0f ? kScale * v : kAlphaScale * (__expf(v) - 1.0f);
}

__device__ __forceinline__ unsigned short f2bf(float f) {
    unsigned int u = __float_as_uint(f);
    u += 0x7fffu + ((u >> 16) & 1u);   // RNE
    return (unsigned short)(u >> 16);
}

// ---------------- kernel 1: dots partials ----------------
// grid 512 (= B*64 pixel-tiles of 64 px), block 256.
// Thread = one (member, pixel) row; x row lives in 64 VGPRs; W via scalar loads.
// Channels processed in 4 quarters so fp32 K/Q tiles fit in <64 KiB LDS.
#define K1_CH 4
#define KCS 18    // sK c-stride (16 px padded to 18)
#define KIS 292   // sK member-stride (16*18+4; ≡4 mod 8 for bank spread)

__global__ __launch_bounds__(256, 2)
void dots_kernel(const float* __restrict__ x,
                 const float* __restrict__ Wk, const float* __restrict__ bk,
                 const float* __restrict__ Wq, const float* __restrict__ bq,
                 float* __restrict__ wts, float* __restrict__ part,
                 int use_atomic)
{
    __shared__ float sK[E_ * KIS];
    __shared__ float sQ[E_ * KIS];

    const int t   = threadIdx.x;
    const int b   = blockIdx.x >> 6;
    const int blk = blockIdx.x & 63;
    const int im  = t >> 4;          // conv: member ; gram: channel-in-quarter
    const int p   = t & 15;          // pixel in chunk
    const int s   = t & 15;          // gram: (i-block, j-block) selector
    const int ib  = (s >> 2) << 2;
    const int jb  = (s & 3) << 2;

    float acc[4][4][4];
    #pragma unroll
    for (int a0 = 0; a0 < 4; ++a0)
      #pragma unroll
      for (int a1 = 0; a1 < 4; ++a1)
        #pragma unroll
        for (int a2 = 0; a2 < 4; ++a2) acc[a0][a1][a2] = 0.0f;

    for (int chunk = 0; chunk < K1_CH; ++chunk) {
        const int p0 = blk * (16 * K1_CH) + chunk * 16;
        const float* xg = x + ((size_t)(b * E_ + im) * CIN_) * HW_ + p0 + p;
        float xr[64];
        #pragma unroll
        for (int a = 0; a < 64; ++a) xr[a] = xg[(size_t)a * HW_];

        #pragma unroll
        for (int q4 = 0; q4 < 4; ++q4) {
            // conv: K,Q for this channel quarter (W loads are wave-uniform -> s_load)
            for (int cc = 0; cc < 16; ++cc) {
                const int c = q4 * 16 + cc;
                const float* wkr = Wk + c * 64;
                const float* wqr = Wq + c * 64;
                float ka0 = 0.f, ka1 = 0.f, qa0 = 0.f, qa1 = 0.f;
                #pragma unroll
                for (int a = 0; a < 64; a += 2) {
                    ka0 = __fmaf_rn(xr[a],     wkr[a],     ka0);
                    qa0 = __fmaf_rn(xr[a],     wqr[a],     qa0);
                    ka1 = __fmaf_rn(xr[a + 1], wkr[a + 1], ka1);
                    qa1 = __fmaf_rn(xr[a + 1], wqr[a + 1], qa1);
                }
                sK[im * KIS + cc * KCS + p] = selu_f(ka0 + ka1 + bk[c]);
                sQ[im * KIS + cc * KCS + p] = selu_f(qa0 + qa1 + bq[c]);
            }
            __syncthreads();
            // gram: dots[c=q4*16+im][i=ib+u][j=jb+v] += K_i * Q_j over 16 px
            #pragma unroll
            for (int p2 = 0; p2 < 8; ++p2) {
                float2 kv[4], qv[4];
                #pragma unroll
                for (int u = 0; u < 4; ++u)
                    kv[u] = *(const float2*)&sK[(ib + u) * KIS + im * KCS + 2 * p2];
                #pragma unroll
                for (int v = 0; v < 4; ++v)
                    qv[v] = *(const float2*)&sQ[(jb + v) * KIS + im * KCS + 2 * p2];
                #pragma unroll
                for (int u = 0; u < 4; ++u)
                    #pragma unroll
                    for (int v = 0; v < 4; ++v)
                        acc[q4][u][v] = __fmaf_rn(kv[u].y, qv[v].y,
                                         __fmaf_rn(kv[u].x, qv[v].x, acc[q4][u][v]));
            }
            __syncthreads();
        }
    }

    if (use_atomic) {
        #pragma unroll
        for (int q4 = 0; q4 < 4; ++q4)
          #pragma unroll
          for (int u = 0; u < 4; ++u)
            #pragma unroll
            for (int v = 0; v < 4; ++v)
              atomicAdd(&wts[(((size_t)b * C_ + (q4 * 16 + im)) * E_ + (ib + u)) * E_ + (jb + v)],
                        acc[q4][u][v]);
    } else {
        float* pb = part + (size_t)blockIdx.x * (C_ * E_ * E_);
        #pragma unroll
        for (int q4 = 0; q4 < 4; ++q4) {
            __syncthreads();
            #pragma unroll
            for (int u = 0; u < 4; ++u)
              #pragma unroll
              for (int v = 0; v < 4; ++v)
                sK[im * 256 + (ib + u) * 16 + (jb + v)] = acc[q4][u][v];
            __syncthreads();
            for (int e = t; e < 4096; e += 256)
                pb[q4 * 4096 + e] = sK[e];
        }
    }
}

// ---------------- kernel 2a: reduce partials ----------------
__global__ __launch_bounds__(256)
void reduce_kernel(const float* __restrict__ part, float* __restrict__ wts)
{
    const int tid = blockIdx.x * 256 + threadIdx.x;  // 0..32767 float4 slots
    const int b   = tid >> 12;
    const int off = tid & 4095;
    float4 s = make_float4(0.f, 0.f, 0.f, 0.f);
    const float* base = part + (size_t)b * 64 * 16384;
    #pragma unroll 8
    for (int blk = 0; blk < 64; ++blk) {
        float4 v = *(const float4*)(base + (size_t)blk * 16384 + off * 4);
        s.x += v.x; s.y += v.y; s.z += v.z; s.w += v.w;
    }
    *(float4*)(wts + (size_t)b * 16384 + off * 4) = s;
}

// ---------------- kernel 2b: softmax over i ----------------
__global__ __launch_bounds__(256)
void softmax_kernel(float* __restrict__ wts)
{
    const int tid = blockIdx.x * 256 + threadIdx.x;  // 8192 = B*C*E(j)
    const int j   = tid & 15;
    const int bc  = tid >> 4;
    float* base = wts + (size_t)bc * 256 + j;
    float v[16];
    #pragma unroll
    for (int i = 0; i < 16; ++i) v[i] = base[i * 16];
    float m = v[0];
    #pragma unroll
    for (int i = 1; i < 16; ++i) m = fmaxf(m, v[i]);
    float sum = 0.f;
    #pragma unroll
    for (int i = 0; i < 16; ++i) { v[i] = __expf(v[i] - m); sum += v[i]; }
    const float r = 1.0f / sum;
    #pragma unroll
    for (int i = 0; i < 16; ++i) base[i * 16] = v[i] * r;
}

// ---------------- kernel 3: V conv + weighted combine + selu ----------------
// grid 1024 (= B*128 tiles of 32 px), block 256.
// out[b,j,c,p] = selu( sum_i w[b,c,i,j] * V[b,i,c,p] )   (mean cancels: sum_i w = 1)
#define K3_CH 2
#define VCS 20      // sV c-stride (ushort; mult of 4 for b64-aligned reads)
#define VIS 1284    // sV member-stride (64*20+4)

__global__ __launch_bounds__(256, 2)
void out_kernel(const float* __restrict__ x,
                const float* __restrict__ Wv, const float* __restrict__ bv,
                const float* __restrict__ wts, float* __restrict__ out)
{
    __shared__ unsigned short sV[E_ * VIS];   // V staged as bf16 (error-tolerant path)

    const int t   = threadIdx.x;
    const int b   = blockIdx.x >> 7;
    const int blk = blockIdx.x & 127;
    const int im  = t >> 4;     // conv: member
    const int p   = t & 15;     // conv: pixel
    const int c   = t >> 2;     // combine: channel
    const int q   = t & 3;      // combine: j-quad

    for (int chunk = 0; chunk < K3_CH; ++chunk) {
        const int p0 = blk * (16 * K3_CH) + chunk * 16;
        const float* xg = x + ((size_t)(b * E_ + im) * CIN_) * HW_ + p0 + p;
        float xr[64];
        #pragma unroll
        for (int a = 0; a < 64; ++a) xr[a] = xg[(size_t)a * HW_];

        for (int cg = 0; cg < 64; ++cg) {
            const float* wvr = Wv + cg * 64;
            float v0 = 0.f, v1 = 0.f;
            #pragma unroll
            for (int a = 0; a < 64; a += 2) {
                v0 = __fmaf_rn(xr[a],     wvr[a],     v0);
                v1 = __fmaf_rn(xr[a + 1], wvr[a + 1], v1);
            }
            sV[im * VIS + cg * VCS + p] = f2bf(v0 + v1 + bv[cg]);
        }
        __syncthreads();

        float acc2[4][16];
        #pragma unroll
        for (int jj = 0; jj < 4; ++jj)
            #pragma unroll
            for (int pp = 0; pp < 16; ++pp) acc2[jj][pp] = 0.f;

        #pragma unroll 4
        for (int i2 = 0; i2 < 16; ++i2) {
            const float4 w4 = *(const float4*)&wts[(((size_t)b * C_ + c) * E_ + i2) * E_ + 4 * q];
            const unsigned short* vp = &sV[i2 * VIS + c * VCS];
            float vv[16];
            #pragma unroll
            for (int pq = 0; pq < 4; ++pq) {
                const uint2 u = *(const uint2*)(vp + 4 * pq);
                vv[4 * pq + 0] = __uint_as_float(u.x << 16);
                vv[4 * pq + 1] = __uint_as_float(u.x & 0xffff0000u);
                vv[4 * pq + 2] = __uint_as_float(u.y << 16);
                vv[4 * pq + 3] = __uint_as_float(u.y & 0xffff0000u);
            }
            const float wj0 = w4.x, wj1 = w4.y, wj2 = w4.z, wj3 = w4.w;
            #pragma unroll
            for (int pp = 0; pp < 16; ++pp) {
                acc2[0][pp] = __fmaf_rn(wj0, vv[pp], acc2[0][pp]);
                acc2[1][pp] = __fmaf_rn(wj1, vv[pp], acc2[1][pp]);
                acc2[2][pp] = __fmaf_rn(wj2, vv[pp], acc2[2][pp]);
                acc2[3][pp] = __fmaf_rn(wj3, vv[pp], acc2[3][pp]);
            }
        }

        #pragma unroll
        for (int jj = 0; jj < 4; ++jj) {
            const int j = 4 * q + jj;
            float* op = out + ((size_t)((b * E_ + j) * C_ + c)) * HW_ + p0;
            #pragma unroll
            for (int pq = 0; pq < 4; ++pq) {
                float4 o;
                o.x = selu_f(acc2[jj][4 * pq + 0]);
                o.y = selu_f(acc2[jj][4 * pq + 1]);
                o.z = selu_f(acc2[jj][4 * pq + 2]);
                o.w = selu_f(acc2[jj][4 * pq + 3]);
                *(float4*)(op + 4 * pq) = o;
            }
        }
        __syncthreads();
    }
}

extern "C" void kernel_launch(void* const* d_in, const int* in_sizes, int n_in,
                              void* d_out, int out_size, void* d_ws, size_t ws_size,
                              hipStream_t stream)
{
    (void)in_sizes; (void)n_in; (void)out_size;
    const float* x  = (const float*)d_in[0];
    const float* Wv = (const float*)d_in[1];
    const float* bv = (const float*)d_in[2];
    const float* Wk = (const float*)d_in[3];
    const float* bk = (const float*)d_in[4];
    const float* Wq = (const float*)d_in[5];
    const float* bq = (const float*)d_in[6];
    float* out = (float*)d_out;

    float* wts  = (float*)d_ws;                         // B*C*E*E = 131072 fl (dots -> weights)
    float* part = wts + (size_t)B_ * C_ * E_ * E_;      // 512 blocks * 16384 fl partials
    const size_t need = ((size_t)B_ * C_ * E_ * E_ + (size_t)512 * C_ * E_ * E_) * sizeof(float);
    const int use_atomic = (ws_size < need) ? 1 : 0;

    if (use_atomic)
        hipMemsetAsync(d_ws, 0, (size_t)B_ * C_ * E_ * E_ * sizeof(float), stream);

    dots_kernel<<<dim3(512), dim3(256), 0, stream>>>(x, Wk, bk, Wq, bq, wts, part, use_atomic);
    if (!use_atomic)
        reduce_kernel<<<dim3(128), dim3(256), 0, stream>>>(part, wts);
    softmax_kernel<<<dim3(32), dim3(256), 0, stream>>>(wts);
    out_kernel<<<dim3(1024), dim3(256), 0, stream>>>(x, Wv, bv, wts, out);
}

// Round 2
// 468.379 us; speedup vs baseline: 1.6856x; 1.6856x over previous
//
#include <hip/hip_runtime.h>
#include <cstdint>
#include <cstddef>

#define B_   8
#define E_   16
#define CIN_ 64
#define C_   64
#define HW_  4096

typedef __attribute__((ext_vector_type(8))) short short8;
typedef __attribute__((ext_vector_type(4))) float floatx4;

// selu(x) = scale*x (x>0) ; scale*alpha*(exp(x)-1) (x<=0)
__device__ __forceinline__ float selu_f(float v) {
    const float kAlphaScale = 1.7580993408473766f;  // alpha*scale
    const float kScale      = 1.0507009873554805f;
    return v > 0.0f ? kScale * v : kAlphaScale * (__expf(v) - 1.0f);
}

__device__ __forceinline__ unsigned short f2bf(float f) {
    unsigned int u = __float_as_uint(f);
    u += 0x7fffu + ((u >> 16) & 1u);   // RNE
    return (unsigned short)(u >> 16);
}
__device__ __forceinline__ float bf2f(unsigned short h) {
    return __uint_as_float(((unsigned int)h) << 16);
}

#define WPAD 72   // W LDS row pad: 64 -> 72 bf16 (144B) breaks 32-bank stride

// stage 64x64 fp32 W -> LDS hi/lo bf16 [64][WPAD]
__device__ __forceinline__ void stage_w(const float* __restrict__ W,
                                        unsigned short* Wh, unsigned short* Wl, int t) {
    for (int idx = t; idx < 4096; idx += 256) {
        const int c = idx >> 6, k = idx & 63;
        const float f = W[idx];
        const unsigned short h = f2bf(f);
        Wh[c * WPAD + k] = h;
        Wl[c * WPAD + k] = f2bf(f - bf2f(h));
    }
}

// ---------------- kernel 1: K/Q conv (MFMA) + gram partials ----------------
// grid 512 (= B*64 px-tiles of 64), block 256 (4 waves).
// Wave w convs members 4w..4w+3 via mfma_f32_16x16x32_bf16 with hi/lo split;
// gram over members stays fp32 VALU (round-1 verified code).
#define K1_CH 4
#define KCS 18    // sK c-stride (16 px padded to 18)
#define KIS 292   // sK member-stride (16*18+4)

__global__ __launch_bounds__(256, 2)
void dots_kernel(const float* __restrict__ x,
                 const float* __restrict__ Wk, const float* __restrict__ bk,
                 const float* __restrict__ Wq, const float* __restrict__ bq,
                 float* __restrict__ wts, float* __restrict__ part,
                 int use_atomic)
{
    __shared__ float sK[E_ * KIS];
    __shared__ float sQ[E_ * KIS];
    __shared__ __align__(16) unsigned short Wkh[64 * WPAD], Wkl[64 * WPAD];
    __shared__ __align__(16) unsigned short Wqh[64 * WPAD], Wql[64 * WPAD];

    const int t    = threadIdx.x;
    const int b    = blockIdx.x >> 6;
    const int blk  = blockIdx.x & 63;
    const int wv   = t >> 6;          // wave id: members 4wv..4wv+3
    const int lane = t & 63;
    const int quad = lane >> 4;
    const int pxl  = lane & 15;       // B-frag n / D col
    const int m16  = lane & 15;       // A-frag m
    // gram mapping (block-wide, from round 1)
    const int gc = t >> 4;            // channel-in-quarter
    const int s  = t & 15;
    const int ib = (s >> 2) << 2;
    const int jb = (s & 3) << 2;

    stage_w(Wk, Wkh, Wkl, t);
    stage_w(Wq, Wqh, Wql, t);

    float acc[4][4][4];
    #pragma unroll
    for (int a0 = 0; a0 < 4; ++a0)
      #pragma unroll
      for (int a1 = 0; a1 < 4; ++a1)
        #pragma unroll
        for (int a2 = 0; a2 < 4; ++a2) acc[a0][a1][a2] = 0.0f;

    __syncthreads();   // W staged

    for (int chunk = 0; chunk < K1_CH; ++chunk) {
        const int p0 = blk * (16 * K1_CH) + chunk * 16;

        // x B-frags: lane holds x[cin=kk*32+quad*8+j][px=p0+pxl], hi/lo bf16
        short8 xh[4][2], xl[4][2];
        #pragma unroll
        for (int mi = 0; mi < 4; ++mi) {
            const int im = 4 * wv + mi;
            const float* xg = x + ((size_t)(b * E_ + im) * CIN_) * HW_ + p0 + pxl;
            #pragma unroll
            for (int kk = 0; kk < 2; ++kk) {
                float xv[8];
                #pragma unroll
                for (int j = 0; j < 8; ++j)
                    xv[j] = xg[(size_t)(kk * 32 + quad * 8 + j) * HW_];
                #pragma unroll
                for (int j = 0; j < 8; ++j) {
                    const unsigned short h = f2bf(xv[j]);
                    xh[mi][kk][j] = (short)h;
                    xl[mi][kk][j] = (short)f2bf(xv[j] - bf2f(h));
                }
            }
        }

        for (int q4 = 0; q4 < 4; ++q4) {
            // ---- K conv for this channel quarter ----
            {
                short8 ah[2], al[2];
                #pragma unroll
                for (int kk = 0; kk < 2; ++kk) {
                    const int off = (q4 * 16 + m16) * WPAD + kk * 32 + quad * 8;
                    ah[kk] = *(const short8*)&Wkh[off];
                    al[kk] = *(const short8*)&Wkl[off];
                }
                float bkv[4];
                #pragma unroll
                for (int r = 0; r < 4; ++r) bkv[r] = bk[q4 * 16 + quad * 4 + r];
                #pragma unroll
                for (int mi = 0; mi < 4; ++mi) {
                    floatx4 d = {0.f, 0.f, 0.f, 0.f};
                    #pragma unroll
                    for (int kk = 0; kk < 2; ++kk) {
                        d = __builtin_amdgcn_mfma_f32_16x16x32_bf16(ah[kk], xh[mi][kk], d, 0, 0, 0);
                        d = __builtin_amdgcn_mfma_f32_16x16x32_bf16(ah[kk], xl[mi][kk], d, 0, 0, 0);
                        d = __builtin_amdgcn_mfma_f32_16x16x32_bf16(al[kk], xh[mi][kk], d, 0, 0, 0);
                    }
                    const int im = 4 * wv + mi;
                    #pragma unroll
                    for (int r = 0; r < 4; ++r)
                        sK[im * KIS + (quad * 4 + r) * KCS + pxl] = selu_f(d[r] + bkv[r]);
                }
            }
            // ---- Q conv for this channel quarter ----
            {
                short8 ah[2], al[2];
                #pragma unroll
                for (int kk = 0; kk < 2; ++kk) {
                    const int off = (q4 * 16 + m16) * WPAD + kk * 32 + quad * 8;
                    ah[kk] = *(const short8*)&Wqh[off];
                    al[kk] = *(const short8*)&Wql[off];
                }
                float bqv[4];
                #pragma unroll
                for (int r = 0; r < 4; ++r) bqv[r] = bq[q4 * 16 + quad * 4 + r];
                #pragma unroll
                for (int mi = 0; mi < 4; ++mi) {
                    floatx4 d = {0.f, 0.f, 0.f, 0.f};
                    #pragma unroll
                    for (int kk = 0; kk < 2; ++kk) {
                        d = __builtin_amdgcn_mfma_f32_16x16x32_bf16(ah[kk], xh[mi][kk], d, 0, 0, 0);
                        d = __builtin_amdgcn_mfma_f32_16x16x32_bf16(ah[kk], xl[mi][kk], d, 0, 0, 0);
                        d = __builtin_amdgcn_mfma_f32_16x16x32_bf16(al[kk], xh[mi][kk], d, 0, 0, 0);
                    }
                    const int im = 4 * wv + mi;
                    #pragma unroll
                    for (int r = 0; r < 4; ++r)
                        sQ[im * KIS + (quad * 4 + r) * KCS + pxl] = selu_f(d[r] + bqv[r]);
                }
            }
            __syncthreads();
            // ---- gram: dots[c=q4*16+gc][i=ib+u][j=jb+v] += K_i*Q_j over 16 px ----
            #pragma unroll
            for (int p2 = 0; p2 < 8; ++p2) {
                float2 kv[4], qv[4];
                #pragma unroll
                for (int u = 0; u < 4; ++u)
                    kv[u] = *(const float2*)&sK[(ib + u) * KIS + gc * KCS + 2 * p2];
                #pragma unroll
                for (int v = 0; v < 4; ++v)
                    qv[v] = *(const float2*)&sQ[(jb + v) * KIS + gc * KCS + 2 * p2];
                #pragma unroll
                for (int u = 0; u < 4; ++u)
                    #pragma unroll
                    for (int v = 0; v < 4; ++v)
                        acc[q4][u][v] = __fmaf_rn(kv[u].y, qv[v].y,
                                         __fmaf_rn(kv[u].x, qv[v].x, acc[q4][u][v]));
            }
            __syncthreads();
        }
    }

    if (use_atomic) {
        #pragma unroll
        for (int q4 = 0; q4 < 4; ++q4)
          #pragma unroll
          for (int u = 0; u < 4; ++u)
            #pragma unroll
            for (int v = 0; v < 4; ++v)
              atomicAdd(&wts[(((size_t)b * C_ + (q4 * 16 + gc)) * E_ + (ib + u)) * E_ + (jb + v)],
                        acc[q4][u][v]);
    } else {
        float* pb = part + (size_t)blockIdx.x * (C_ * E_ * E_);
        #pragma unroll
        for (int q4 = 0; q4 < 4; ++q4) {
            __syncthreads();
            #pragma unroll
            for (int u = 0; u < 4; ++u)
              #pragma unroll
              for (int v = 0; v < 4; ++v)
                sK[gc * 256 + (ib + u) * 16 + (jb + v)] = acc[q4][u][v];
            __syncthreads();
            for (int e = t; e < 4096; e += 256)
                pb[q4 * 4096 + e] = sK[e];
        }
    }
}

// ---------------- kernel 2a: reduce partials ----------------
__global__ __launch_bounds__(256)
void reduce_kernel(const float* __restrict__ part, float* __restrict__ wts)
{
    const int tid = blockIdx.x * 256 + threadIdx.x;  // 0..32767 float4 slots
    const int b   = tid >> 12;
    const int off = tid & 4095;
    float4 sum = make_float4(0.f, 0.f, 0.f, 0.f);
    const float* base = part + (size_t)b * 64 * 16384;
    #pragma unroll 8
    for (int blk = 0; blk < 64; ++blk) {
        float4 v = *(const float4*)(base + (size_t)blk * 16384 + off * 4);
        sum.x += v.x; sum.y += v.y; sum.z += v.z; sum.w += v.w;
    }
    *(float4*)(wts + (size_t)b * 16384 + off * 4) = sum;
}

// ---------------- kernel 2b: softmax over i ----------------
__global__ __launch_bounds__(256)
void softmax_kernel(float* __restrict__ wts)
{
    const int tid = blockIdx.x * 256 + threadIdx.x;  // 8192 = B*C*E(j)
    const int j   = tid & 15;
    const int bc  = tid >> 4;
    float* base = wts + (size_t)bc * 256 + j;
    float v[16];
    #pragma unroll
    for (int i = 0; i < 16; ++i) v[i] = base[i * 16];
    float m = v[0];
    #pragma unroll
    for (int i = 1; i < 16; ++i) m = fmaxf(m, v[i]);
    float sum = 0.f;
    #pragma unroll
    for (int i = 0; i < 16; ++i) { v[i] = __expf(v[i] - m); sum += v[i]; }
    const float r = 1.0f / sum;
    #pragma unroll
    for (int i = 0; i < 16; ++i) base[i * 16] = v[i] * r;
}

// ---------------- kernel 3: V conv (MFMA) + weighted combine + selu ----------------
// grid 1024 (= B*128 tiles of 32 px), block 256.
// out[b,j,c,p] = selu( sum_i w[b,c,i,j] * V[b,i,c,p] )   (mean cancels: sum_i w = 1)
#define K3_CH 2
#define VCS 20      // sV c-stride (ushort; mult of 4 for aligned uint2 reads)
#define VIS 1284    // sV member-stride (64*20+4)

__global__ __launch_bounds__(256, 2)
void out_kernel(const float* __restrict__ x,
                const float* __restrict__ Wv, const float* __restrict__ bv,
                const float* __restrict__ wts, float* __restrict__ out)
{
    __shared__ __align__(16) unsigned short sV[E_ * VIS];   // V staged bf16
    __shared__ __align__(16) unsigned short Wvh[64 * WPAD], Wvl[64 * WPAD];

    const int t    = threadIdx.x;
    const int b    = blockIdx.x >> 7;
    const int blk  = blockIdx.x & 127;
    const int wv   = t >> 6;
    const int lane = t & 63;
    const int quad = lane >> 4;
    const int pxl  = lane & 15;
    const int m16  = lane & 15;
    const int c    = t >> 2;     // combine: channel
    const int q    = t & 3;      // combine: j-quad

    stage_w(Wv, Wvh, Wvl, t);
    __syncthreads();

    for (int chunk = 0; chunk < K3_CH; ++chunk) {
        const int p0 = blk * (16 * K3_CH) + chunk * 16;

        short8 xh[4][2], xl[4][2];
        #pragma unroll
        for (int mi = 0; mi < 4; ++mi) {
            const int im = 4 * wv + mi;
            const float* xg = x + ((size_t)(b * E_ + im) * CIN_) * HW_ + p0 + pxl;
            #pragma unroll
            for (int kk = 0; kk < 2; ++kk) {
                float xv[8];
                #pragma unroll
                for (int j = 0; j < 8; ++j)
                    xv[j] = xg[(size_t)(kk * 32 + quad * 8 + j) * HW_];
                #pragma unroll
                for (int j = 0; j < 8; ++j) {
                    const unsigned short h = f2bf(xv[j]);
                    xh[mi][kk][j] = (short)h;
                    xl[mi][kk][j] = (short)f2bf(xv[j] - bf2f(h));
                }
            }
        }

        #pragma unroll
        for (int cb = 0; cb < 4; ++cb) {
            short8 ah[2], al[2];
            #pragma unroll
            for (int kk = 0; kk < 2; ++kk) {
                const int off = (cb * 16 + m16) * WPAD + kk * 32 + quad * 8;
                ah[kk] = *(const short8*)&Wvh[off];
                al[kk] = *(const short8*)&Wvl[off];
            }
            float bvv[4];
            #pragma unroll
            for (int r = 0; r < 4; ++r) bvv[r] = bv[cb * 16 + quad * 4 + r];
            #pragma unroll
            for (int mi = 0; mi < 4; ++mi) {
                floatx4 d = {0.f, 0.f, 0.f, 0.f};
                #pragma unroll
                for (int kk = 0; kk < 2; ++kk) {
                    d = __builtin_amdgcn_mfma_f32_16x16x32_bf16(ah[kk], xh[mi][kk], d, 0, 0, 0);
                    d = __builtin_amdgcn_mfma_f32_16x16x32_bf16(ah[kk], xl[mi][kk], d, 0, 0, 0);
                    d = __builtin_amdgcn_mfma_f32_16x16x32_bf16(al[kk], xh[mi][kk], d, 0, 0, 0);
                }
                const int im = 4 * wv + mi;
                #pragma unroll
                for (int r = 0; r < 4; ++r)
                    sV[im * VIS + (cb * 16 + quad * 4 + r) * VCS + pxl] = f2bf(d[r] + bvv[r]);
            }
        }
        __syncthreads();

        // ---- combine (round-1 verified) ----
        float acc2[4][16];
        #pragma unroll
        for (int jj = 0; jj < 4; ++jj)
            #pragma unroll
            for (int pp = 0; pp < 16; ++pp) acc2[jj][pp] = 0.f;

        #pragma unroll 4
        for (int i2 = 0; i2 < 16; ++i2) {
            const float4 w4 = *(const float4*)&wts[(((size_t)b * C_ + c) * E_ + i2) * E_ + 4 * q];
            const unsigned short* vp = &sV[i2 * VIS + c * VCS];
            float vvv[16];
            #pragma unroll
            for (int pq = 0; pq < 4; ++pq) {
                const uint2 u = *(const uint2*)(vp + 4 * pq);
                vvv[4 * pq + 0] = __uint_as_float(u.x << 16);
                vvv[4 * pq + 1] = __uint_as_float(u.x & 0xffff0000u);
                vvv[4 * pq + 2] = __uint_as_float(u.y << 16);
                vvv[4 * pq + 3] = __uint_as_float(u.y & 0xffff0000u);
            }
            const float wj0 = w4.x, wj1 = w4.y, wj2 = w4.z, wj3 = w4.w;
            #pragma unroll
            for (int pp = 0; pp < 16; ++pp) {
                acc2[0][pp] = __fmaf_rn(wj0, vvv[pp], acc2[0][pp]);
                acc2[1][pp] = __fmaf_rn(wj1, vvv[pp], acc2[1][pp]);
                acc2[2][pp] = __fmaf_rn(wj2, vvv[pp], acc2[2][pp]);
                acc2[3][pp] = __fmaf_rn(wj3, vvv[pp], acc2[3][pp]);
            }
        }

        #pragma unroll
        for (int jj = 0; jj < 4; ++jj) {
            const int j = 4 * q + jj;
            float* op = out + ((size_t)((b * E_ + j) * C_ + c)) * HW_ + p0;
            #pragma unroll
            for (int pq = 0; pq < 4; ++pq) {
                float4 o;
                o.x = selu_f(acc2[jj][4 * pq + 0]);
                o.y = selu_f(acc2[jj][4 * pq + 1]);
                o.z = selu_f(acc2[jj][4 * pq + 2]);
                o.w = selu_f(acc2[jj][4 * pq + 3]);
                *(float4*)(op + 4 * pq) = o;
            }
        }
        __syncthreads();
    }
}

extern "C" void kernel_launch(void* const* d_in, const int* in_sizes, int n_in,
                              void* d_out, int out_size, void* d_ws, size_t ws_size,
                              hipStream_t stream)
{
    (void)in_sizes; (void)n_in; (void)out_size;
    const float* x  = (const float*)d_in[0];
    const float* Wv = (const float*)d_in[1];
    const float* bv = (const float*)d_in[2];
    const float* Wk = (const float*)d_in[3];
    const float* bk = (const float*)d_in[4];
    const float* Wq = (const float*)d_in[5];
    const float* bq = (const float*)d_in[6];
    float* out = (float*)d_out;

    float* wts  = (float*)d_ws;                         // B*C*E*E = 131072 floats
    float* part = wts + (size_t)B_ * C_ * E_ * E_;      // 512 blocks * 16384 floats
    const size_t need = ((size_t)B_ * C_ * E_ * E_ + (size_t)512 * C_ * E_ * E_) * sizeof(float);
    const int use_atomic = (ws_size < need) ? 1 : 0;

    if (use_atomic)
        hipMemsetAsync(d_ws, 0, (size_t)B_ * C_ * E_ * E_ * sizeof(float), stream);

    dots_kernel<<<dim3(512), dim3(256), 0, stream>>>(x, Wk, bk, Wq, bq, wts, part, use_atomic);
    if (!use_atomic)
        reduce_kernel<<<dim3(128), dim3(256), 0, stream>>>(part, wts);
    softmax_kernel<<<dim3(32), dim3(256), 0, stream>>>(wts);
    out_kernel<<<dim3(1024), dim3(256), 0, stream>>>(x, Wv, bv, wts, out);
}